// Round 1
// baseline (857.568 us; speedup 1.0000x reference)
//
#include <hip/hip_runtime.h>
#include <math.h>

// Problem constants
#define NH     8
#define HD     64
#define NTOK   1024    // H*W = 32*32
#define CIN    256
#define HIDDEN 512     // NH*HD
#define O3     1536    // 3*HIDDEN
#define BATCH  8
#define ATT_SCALE 0.125f  // 1/sqrt(64)

// ---------------------------------------------------------------------------
// Generic tiled GEMM: C[b][m][p] = sum_k A[m][k] * B[b][k][p] (+ bias[m])
// A: [M][K] row-major (shared across batch). B: [b][K][NTOK]. C: [b][M][NTOK].
// 64x64 output tile per block, 256 threads, 4x4 register tile per thread,
// K staged in 64-chunks through LDS.
// ---------------------------------------------------------------------------
template <int M, int K, bool HAS_BIAS>
__global__ __launch_bounds__(256, 2)
void gemm_kernel(const float* __restrict__ A, const float* __restrict__ Bm,
                 const float* __restrict__ bias, float* __restrict__ C)
{
    __shared__ float As[64][68];   // As[m][k]   (+4 pad: 2-way banks max)
    __shared__ float Bs[64][68];   // Bs[k][p]
    const int tj = threadIdx.x & 15;   // output col group (4 cols)
    const int ti = threadIdx.x >> 4;   // output row group (4 rows), 0..15
    const int p0 = blockIdx.x * 64;
    const int m0 = blockIdx.y * 64;
    const int b  = blockIdx.z;

    const float* Bb = Bm + (size_t)b * K * NTOK;
    float*       Cb = C  + (size_t)b * M * NTOK;

    float acc[4][4] = {};

    for (int kc = 0; kc < K; kc += 64) {
        __syncthreads();
        #pragma unroll
        for (int ii = 0; ii < 4; ++ii) {
            const int r = ti + 16 * ii;
            // A tile: rows m0+r, cols kc+4*tj  (coalesced 256B per 16 lanes)
            *(float4*)&As[r][4 * tj] =
                *(const float4*)&A[(size_t)(m0 + r) * K + kc + 4 * tj];
            // B tile: rows kc+r, cols p0+4*tj
            *(float4*)&Bs[r][4 * tj] =
                *(const float4*)&Bb[(size_t)(kc + r) * NTOK + p0 + 4 * tj];
        }
        __syncthreads();

        #pragma unroll
        for (int k = 0; k < 64; ++k) {
            const float4 b4 = *(const float4*)&Bs[k][4 * tj];
            float av[4];
            #pragma unroll
            for (int r = 0; r < 4; ++r) av[r] = As[4 * ti + r][k];  // broadcast reads
            const float bv[4] = {b4.x, b4.y, b4.z, b4.w};
            #pragma unroll
            for (int r = 0; r < 4; ++r)
                #pragma unroll
                for (int c = 0; c < 4; ++c)
                    acc[r][c] += av[r] * bv[c];
        }
    }

    #pragma unroll
    for (int r = 0; r < 4; ++r) {
        const int m = m0 + 4 * ti + r;
        float bv = 0.0f;
        if (HAS_BIAS) bv = bias[m];
        float4 o;
        o.x = acc[r][0] + bv; o.y = acc[r][1] + bv;
        o.z = acc[r][2] + bv; o.w = acc[r][3] + bv;
        *(float4*)&Cb[(size_t)m * NTOK + p0 + 4 * tj] = o;
    }
}

// ---------------------------------------------------------------------------
// Flash-style fused attention.
// qkv layout: [b][o][p], o = s*512 + h*64 + d  (s=0:Q, 1:K, 2:V), p = token.
// Block = (b, h, 64-query tile). Never materializes the 1024x1024 S matrix.
// S[i][j] = sum_d Q[d][i]*K[d][j]*scale ; online softmax ; O[i][d] += P*V.
// Output: attn_out[b][h*64+d][p=i].
// ---------------------------------------------------------------------------
__global__ __launch_bounds__(256, 2)
void attn_kernel(const float* __restrict__ qkv, float* __restrict__ attn_out)
{
    __shared__ float Qs[64][68];   // Qs[d][i], pre-scaled
    __shared__ float Ks[64][68];   // Ks[d][j]; reused as Os[d][i] for store
    __shared__ float Vs[64][68];   // Vs[d][j]
    __shared__ float Ps[64][68];   // Ps[i][j]

    const int tj = threadIdx.x & 15;
    const int ti = threadIdx.x >> 4;   // 0..15
    const int i0 = blockIdx.x * 64;    // query tile start
    const int h  = blockIdx.y;
    const int b  = blockIdx.z;

    const float* Qg = qkv + ((size_t)b * O3 + 0 * HIDDEN + h * HD) * NTOK;
    const float* Kg = qkv + ((size_t)b * O3 + 1 * HIDDEN + h * HD) * NTOK;
    const float* Vg = qkv + ((size_t)b * O3 + 2 * HIDDEN + h * HD) * NTOK;

    // Load Q tile once, pre-multiplied by the softmax scale.
    #pragma unroll
    for (int ii = 0; ii < 4; ++ii) {
        const int d = ti + 16 * ii;
        float4 q = *(const float4*)&Qg[(size_t)d * NTOK + i0 + 4 * tj];
        q.x *= ATT_SCALE; q.y *= ATT_SCALE; q.z *= ATT_SCALE; q.w *= ATT_SCALE;
        *(float4*)&Qs[d][4 * tj] = q;
    }

    float m_run[4], l_run[4], o_acc[4][4];
    #pragma unroll
    for (int r = 0; r < 4; ++r) {
        m_run[r] = -INFINITY; l_run[r] = 0.0f;
        #pragma unroll
        for (int c = 0; c < 4; ++c) o_acc[r][c] = 0.0f;
    }

    for (int jt = 0; jt < NTOK / 64; ++jt) {
        const int j0 = jt * 64;
        __syncthreads();   // previous PV reads of Ks/Vs/Ps done
        #pragma unroll
        for (int ii = 0; ii < 4; ++ii) {
            const int d = ti + 16 * ii;
            *(float4*)&Ks[d][4 * tj] = *(const float4*)&Kg[(size_t)d * NTOK + j0 + 4 * tj];
            *(float4*)&Vs[d][4 * tj] = *(const float4*)&Vg[(size_t)d * NTOK + j0 + 4 * tj];
        }
        __syncthreads();

        // ---- S tile: 4x4 per thread, rows i=4*ti+r, cols j=4*tj+c ----
        float s[4][4] = {};
        #pragma unroll
        for (int d = 0; d < 64; ++d) {
            const float4 q4 = *(const float4*)&Qs[d][4 * ti];  // broadcast
            const float4 k4 = *(const float4*)&Ks[d][4 * tj];
            const float qa[4] = {q4.x, q4.y, q4.z, q4.w};
            const float ka[4] = {k4.x, k4.y, k4.z, k4.w};
            #pragma unroll
            for (int r = 0; r < 4; ++r)
                #pragma unroll
                for (int c = 0; c < 4; ++c)
                    s[r][c] += qa[r] * ka[c];
        }

        // ---- online softmax (row groups share the 16 tj lanes) ----
        #pragma unroll
        for (int r = 0; r < 4; ++r) {
            float mt = fmaxf(fmaxf(s[r][0], s[r][1]), fmaxf(s[r][2], s[r][3]));
            #pragma unroll
            for (int off = 1; off < 16; off <<= 1)
                mt = fmaxf(mt, __shfl_xor(mt, off));
            const float m_new = fmaxf(m_run[r], mt);
            const float corr  = __expf(m_run[r] - m_new);
            float p[4], lt = 0.0f;
            #pragma unroll
            for (int c = 0; c < 4; ++c) { p[c] = __expf(s[r][c] - m_new); lt += p[c]; }
            #pragma unroll
            for (int off = 1; off < 16; off <<= 1)
                lt += __shfl_xor(lt, off);
            l_run[r] = l_run[r] * corr + lt;
            m_run[r] = m_new;
            #pragma unroll
            for (int c = 0; c < 4; ++c) o_acc[r][c] *= corr;
            *(float4*)&Ps[4 * ti + r][4 * tj] = make_float4(p[0], p[1], p[2], p[3]);
        }
        __syncthreads();

        // ---- PV: O[i][d] += sum_j P[i][j] * V[d][j]; thread cols d=tj+16*rr ----
        #pragma unroll
        for (int j = 0; j < 64; j += 4) {
            float4 vv[4];
            #pragma unroll
            for (int rr = 0; rr < 4; ++rr)
                vv[rr] = *(const float4*)&Vs[tj + 16 * rr][j];   // 2-way banks
            #pragma unroll
            for (int r = 0; r < 4; ++r) {
                const float4 p4 = *(const float4*)&Ps[4 * ti + r][j];  // broadcast
                #pragma unroll
                for (int rr = 0; rr < 4; ++rr)
                    o_acc[r][rr] += p4.x * vv[rr].x + p4.y * vv[rr].y +
                                    p4.z * vv[rr].z + p4.w * vv[rr].w;
            }
        }
    }

    // ---- normalize; transpose O through LDS (reuse Ks) for coalesced store ----
    __syncthreads();
    #pragma unroll
    for (int r = 0; r < 4; ++r) {
        const float inv = 1.0f / l_run[r];
        #pragma unroll
        for (int rr = 0; rr < 4; ++rr)
            Ks[tj + 16 * rr][4 * ti + r] = o_acc[r][rr] * inv;  // Os[d][i]
    }
    __syncthreads();
    float* Og = attn_out + ((size_t)b * HIDDEN + h * HD) * NTOK;
    #pragma unroll
    for (int ii = 0; ii < 4; ++ii) {
        const int d = ti + 16 * ii;
        *(float4*)&Og[(size_t)d * NTOK + i0 + 4 * tj] = *(const float4*)&Ks[d][4 * tj];
    }
}

// ---------------------------------------------------------------------------
extern "C" void kernel_launch(void* const* d_in, const int* in_sizes, int n_in,
                              void* d_out, int out_size, void* d_ws, size_t ws_size,
                              hipStream_t stream)
{
    const float* x    = (const float*)d_in[0];   // [8][256][1024]
    const float* Wqkv = (const float*)d_in[1];   // [1536][256]
    const float* Wout = (const float*)d_in[2];   // [256][512]
    const float* bout = (const float*)d_in[3];   // [256]
    float* out = (float*)d_out;                  // [8][256][1024]

    float* qkv  = (float*)d_ws;                          // 8*1536*1024 f32 = 48 MiB
    float* attn = qkv + (size_t)BATCH * O3 * NTOK;       // 8*512*1024  f32 = 16 MiB

    // 1) QKV projection: qkv[b][o][p] = sum_c Wqkv[o][c] * x[b][c][p]
    gemm_kernel<O3, CIN, false>
        <<<dim3(NTOK / 64, O3 / 64, BATCH), 256, 0, stream>>>(Wqkv, x, nullptr, qkv);

    // 2) fused flash attention -> attn[b][h*64+d][p]
    attn_kernel<<<dim3(NTOK / 64, NH, BATCH), 256, 0, stream>>>(qkv, attn);

    // 3) output projection + bias: out[b][c][p] = sum_o Wout[c][o]*attn[b][o][p] + bout[c]
    gemm_kernel<CIN, HIDDEN, true>
        <<<dim3(NTOK / 64, CIN / 64, BATCH), 256, 0, stream>>>(Wout, attn, bout, out);
}